// Round 5
// baseline (186.564 us; speedup 1.0000x reference)
//
#include <hip/hip_runtime.h>

typedef unsigned int u32;
typedef unsigned short u16;
typedef unsigned long long u64;

// Problem constants (from reference setup_inputs):
//   AW = 4194304 words, AD = 16384 docs, T = 8, V = 50000, K = 64
//   INIT_ALPHA = 50/64; eta_inc = (1+a)/(N + K*a), K*a = 50
#define KDIM 64
#define TDIM 8
#define VDIM 50000
#define ADOC 16384

// CWK binning: bucket = (t*V+w)>>9 -> 782 buckets of 512 w-slots x 64 z.
#define NB_CW 782
#define OCW_STRIDE 784           // offs row stride (NB_CW+1 padded)
// DZ binning: bucket = d>>6 -> 256 buckets of 64 docs x 64 z.
#define NB_DZ 256
#define ODZ_STRIDE 260

#define WPB 4096                 // words per phase-1 block (deterministic region)
#define P1T 512                  // phase-1 threads

__device__ __forceinline__ void atomic_add_f32(float* p, float v) {
    unsafeAtomicAdd(p, v);       // native global_atomic_add_f32 (no CAS loop)
}

// ---------------- Phase 1: count -> scan -> route (zero global atomics
// except the tiny CK histogram flush) ----------------
__global__ __launch_bounds__(P1T) void p1_route(
    const int* __restrict__ t_arr, const int* __restrict__ d_arr,
    const int* __restrict__ w_arr, const float* __restrict__ n_arr,
    const int* __restrict__ z_arr,
    u16* __restrict__ rec_cw,    // [nblk][WPB] bucket-grouped cw records
    u32* __restrict__ rec_dz,    // [nblk][WPB] bucket-grouped dz records
    u16* __restrict__ offs_cw,   // [nblk][OCW_STRIDE] per-bucket start offsets
    u16* __restrict__ offs_dz,   // [nblk][ODZ_STRIDE]
    float* __restrict__ outCK, int AW)
{
    __shared__ u32 s_cw[1024];          // counts -> inclusive scan (782 used)
    __shared__ u32 s_dz[256];
    __shared__ u32 cur_cw[NB_CW];       // write cursors
    __shared__ u32 cur_dz[NB_DZ];
    __shared__ u32 ckh[TDIM * KDIM];    // 512

    const int tid = threadIdx.x;
    s_cw[tid] = 0; s_cw[tid + 512] = 0;
    if (tid < 256) s_dz[tid] = 0;
    ckh[tid] = 0;
    __syncthreads();

    const int base = blockIdx.x * WPB;
    const int nw = min(WPB, AW - base);
    const int nq = nw >> 2;             // base is 4-aligned (WPB%4==0)
    const int tail0 = base + (nq << 2);
    const int tail1 = base + nw;

    // ---- Pass A: per-bucket counts ----
    #pragma unroll
    for (int j = 0; j < WPB / 4 / P1T; ++j) {
        const int ql = j * P1T + tid;
        if (ql < nq) {
            const int q = (base >> 2) + ql;
            const int4 t4 = ((const int4*)t_arr)[q];
            const int4 w4 = ((const int4*)w_arr)[q];
            const int4 d4 = ((const int4*)d_arr)[q];
            const int te[4] = {t4.x, t4.y, t4.z, t4.w};
            const int we[4] = {w4.x, w4.y, w4.z, w4.w};
            const int de[4] = {d4.x, d4.y, d4.z, d4.w};
            #pragma unroll
            for (int e = 0; e < 4; ++e) {
                atomicAdd(&s_cw[(u32)(te[e] * VDIM + we[e]) >> 9], 1u);
                atomicAdd(&s_dz[(u32)de[e] >> 6], 1u);
            }
        }
    }
    if (tid == 0) {
        for (int i = tail0; i < tail1; ++i) {
            atomicAdd(&s_cw[(u32)(t_arr[i] * VDIM + w_arr[i]) >> 9], 1u);
            atomicAdd(&s_dz[(u32)d_arr[i] >> 6], 1u);
        }
    }
    __syncthreads();

    // ---- Fused inclusive Hillis-Steele scans (cw: 1024 wide, dz: 256) ----
    for (int dd = 1; dd < 1024; dd <<= 1) {
        const u32 a0 = (tid >= dd) ? s_cw[tid - dd] : 0u;
        const u32 a1 = ((tid + 512) >= dd) ? s_cw[tid + 512 - dd] : 0u;
        u32 b0 = 0;
        if (dd < 256 && tid < 256 && tid >= dd) b0 = s_dz[tid - dd];
        __syncthreads();
        s_cw[tid] += a0; s_cw[tid + 512] += a1;
        if (dd < 256 && tid < 256) s_dz[tid] += b0;
        __syncthreads();
    }

    // ---- Exclusive starts -> LDS cursors + global offsets table ----
    u16* ocw = offs_cw + (size_t)blockIdx.x * OCW_STRIDE;
    u16* odz = offs_dz + (size_t)blockIdx.x * ODZ_STRIDE;
    for (int i = tid; i < NB_CW; i += P1T) {
        const u32 e0 = i ? s_cw[i - 1] : 0u;
        cur_cw[i] = e0;
        ocw[i] = (u16)e0;
    }
    if (tid < NB_DZ) {
        const u32 e0 = tid ? s_dz[tid - 1] : 0u;
        cur_dz[tid] = e0;
        odz[tid] = (u16)e0;
    }
    if (tid == 0) { ocw[NB_CW] = (u16)nw; odz[NB_DZ] = (u16)nw; }
    __syncthreads();

    const float num = 1.0f + 50.0f / 64.0f;  // 1 + alpha
    const float ka  = 50.0f;                 // K * alpha

    // ---- Pass B: emit bucket-grouped records (plain stores) ----
    u16* rcw = rec_cw + (size_t)blockIdx.x * WPB;
    u32* rdz = rec_dz + (size_t)blockIdx.x * WPB;
    #pragma unroll
    for (int j = 0; j < WPB / 4 / P1T; ++j) {
        const int ql = j * P1T + tid;
        if (ql < nq) {
            const int q = (base >> 2) + ql;
            const int4   t4 = ((const int4*)t_arr)[q];
            const int4   w4 = ((const int4*)w_arr)[q];
            const int4   d4 = ((const int4*)d_arr)[q];
            const int4   z4 = ((const int4*)z_arr)[q];
            const float4 n4 = ((const float4*)n_arr)[q];
            const int te[4] = {t4.x, t4.y, t4.z, t4.w};
            const int we[4] = {w4.x, w4.y, w4.z, w4.w};
            const int de[4] = {d4.x, d4.y, d4.z, d4.w};
            const int ze[4] = {z4.x, z4.y, z4.z, z4.w};
            const float ne[4] = {n4.x, n4.y, n4.z, n4.w};
            #pragma unroll
            for (int e = 0; e < 4; ++e) {
                const u32 tw = (u32)(te[e] * VDIM + we[e]);
                const u32 p = atomicAdd(&cur_cw[tw >> 9], 1u);
                rcw[p] = (u16)(((tw & 511u) << 6) | (u32)ze[e]);
                // dz record: key(12b)<<20 | eta_inc in 2^-24 fixed (<2^20 always)
                const u32 efix = (u32)(num / (ne[e] + ka) * 16777216.0f + 0.5f);
                const u32 p2 = atomicAdd(&cur_dz[(u32)de[e] >> 6], 1u);
                rdz[p2] = ((((u32)de[e] & 63u) << 6 | (u32)ze[e]) << 20) | efix;
                atomicAdd(&ckh[((u32)te[e] << 6) | (u32)ze[e]], 1u);
            }
        }
    }
    if (tid == 0) {
        for (int i = tail0; i < tail1; ++i) {
            const u32 tw = (u32)(t_arr[i] * VDIM + w_arr[i]);
            const u32 p = atomicAdd(&cur_cw[tw >> 9], 1u);
            rcw[p] = (u16)(((tw & 511u) << 6) | (u32)z_arr[i]);
            const u32 efix = (u32)(num / (n_arr[i] + ka) * 16777216.0f + 0.5f);
            const u32 p2 = atomicAdd(&cur_dz[(u32)d_arr[i] >> 6], 1u);
            rdz[p2] = ((((u32)d_arr[i] & 63u) << 6 | (u32)z_arr[i]) << 20) | efix;
            atomicAdd(&ckh[((u32)t_arr[i] << 6) | (u32)z_arr[i]], 1u);
        }
    }
    __syncthreads();

    // ---- CK flush: t sorted -> ~64-128 nonzero bins/block ----
    {
        const u32 c = ckh[tid];
        if (c) atomic_add_f32(&outCK[tid], (float)c);
    }
}

// ---------------- Phase 2a: CWK dense histogram + write ----------------
__global__ __launch_bounds__(256) void p2_cwk(
    const u16* __restrict__ rec_cw, const u16* __restrict__ offs_cw,
    const float* __restrict__ inCWK, float* __restrict__ outCWK, int nblk)
{
    __shared__ u32 hist[16384];   // 32768 u16-packed counts (64 KB)
    const int tid = threadIdx.x;
    const u32 bw = blockIdx.x;
    for (int i = tid; i < 16384; i += 256) hist[i] = 0;
    __syncthreads();

    // Each thread replays whole per-block segments (scalar, ~5 recs each).
    for (int b = tid; b < nblk; b += 256) {
        const u16* orow = offs_cw + (size_t)b * OCW_STRIDE;
        const u32 o0 = orow[bw], o1 = orow[bw + 1];
        const u16* rec = rec_cw + (size_t)b * WPB;
        for (u32 i = o0; i < o1; ++i) {
            const u32 s = rec[i];
            atomicAdd(&hist[s >> 1], 1u << ((s & 1u) << 4));
        }
    }
    __syncthreads();

    const u32 g0 = bw << 15;                      // bucket base in CWK
    const u32 NTOT = (u32)TDIM * VDIM * KDIM;     // 25,600,000
    for (int h = tid; h < 16384 / 4; h += 256) {  // 8 slots / iter / thread
        const u32 g = g0 + (u32)h * 8u;
        if (g >= NTOT) continue;                  // tail bucket overhang
        const uint4 pc = ((const uint4*)hist)[h];
        float c[8] = {
            (float)(pc.x & 0xFFFFu), (float)(pc.x >> 16),
            (float)(pc.y & 0xFFFFu), (float)(pc.y >> 16),
            (float)(pc.z & 0xFFFFu), (float)(pc.z >> 16),
            (float)(pc.w & 0xFFFFu), (float)(pc.w >> 16)};
        if (g + 8 <= NTOT) {
            float4 a0 = ((const float4*)inCWK)[g >> 2];
            float4 a1 = ((const float4*)inCWK)[(g >> 2) + 1];
            a0.x += c[0]; a0.y += c[1]; a0.z += c[2]; a0.w += c[3];
            a1.x += c[4]; a1.y += c[5]; a1.z += c[6]; a1.w += c[7];
            ((float4*)outCWK)[g >> 2] = a0;
            ((float4*)outCWK)[(g >> 2) + 1] = a1;
        } else {
            for (u32 e = 0; e < 8 && g + e < NTOT; ++e)
                outCWK[g + e] = inCWK[g + e] + c[e];
        }
    }
}

// ---------------- Phase 2b: CDK + Eta dense accumulate + write ----------------
__global__ __launch_bounds__(256) void p2_dz(
    const u32* __restrict__ rec_dz, const u16* __restrict__ offs_dz,
    const float* __restrict__ inCDK, const float* __restrict__ inEta,
    float* __restrict__ outCDK, float* __restrict__ outEta, int nblk)
{
    __shared__ u64 acc[4096];   // (eta_fixed << 20) | count, 32 KB
    const int tid = threadIdx.x;
    const u32 bd = blockIdx.x;
    for (int i = tid; i < 4096; i += 256) acc[i] = 0ull;
    __syncthreads();

    for (int b = tid; b < nblk; b += 256) {
        const u16* orow = offs_dz + (size_t)b * ODZ_STRIDE;
        const u32 o0 = orow[bd], o1 = orow[bd + 1];
        const u32* rec = rec_dz + (size_t)b * WPB;
        for (u32 i = o0; i < o1; ++i) {
            const u32 r = rec[i];
            atomicAdd(&acc[r >> 20], ((u64)(r & 0xFFFFFu) << 20) | 1ull);
        }
    }
    __syncthreads();

    const u32 g0 = bd << 12;   // base in [AD*K): global = d*64+z = (d>>6)<<12 | s
    for (int s = tid; s < 4096; s += 256) {
        const u64 p = acc[s];
        outCDK[g0 + s] = inCDK[g0 + s] + (float)(u32)(p & 0xFFFFFull);
        outEta[g0 + s] = inEta[g0 + s] + (float)(p >> 20) * (1.0f / 16777216.0f);
    }
}

// ---------------- Generic fallback (safety net) ----------------
__global__ __launch_bounds__(256) void fb_scatter(
    const int* __restrict__ t_arr, const int* __restrict__ d_arr,
    const int* __restrict__ w_arr, const float* __restrict__ n_arr,
    const int* __restrict__ z_arr,
    float* __restrict__ outCDK, float* __restrict__ outCWK,
    float* __restrict__ outCK, float* __restrict__ outEta,
    int AW, int V, int Kd)
{
    const float alpha = 50.0f / (float)Kd;
    const int stride = gridDim.x * blockDim.x;
    for (int i = blockIdx.x * blockDim.x + threadIdx.x; i < AW; i += stride) {
        const int dz = d_arr[i] * Kd + z_arr[i];
        atomic_add_f32(&outCDK[dz], 1.0f);
        atomic_add_f32(&outCWK[(t_arr[i] * V + w_arr[i]) * Kd + z_arr[i]], 1.0f);
        atomic_add_f32(&outCK[t_arr[i] * Kd + z_arr[i]], 1.0f);
        atomic_add_f32(&outEta[dz], (1.0f + alpha) / (n_arr[i] + Kd * alpha));
    }
}

extern "C" void kernel_launch(void* const* d_in, const int* in_sizes, int n_in,
                              void* d_out, int out_size, void* d_ws, size_t ws_size,
                              hipStream_t stream) {
    const int* t_arr = (const int*)d_in[0];     // time_ind_per_word (sorted)
    const int* d_arr = (const int*)d_in[1];     // doc_indexes
    const int* w_arr = (const int*)d_in[2];     // flatW
    const float* n_arr = (const float*)d_in[3]; // N_per_word
    const int* z_arr = (const int*)d_in[4];     // flatZ
    const float* inCDK = (const float*)d_in[5];
    const float* inCWK = (const float*)d_in[6];
    const float* inCK  = (const float*)d_in[7];
    const float* inEta = (const float*)d_in[8];

    const int AW = in_sizes[0];
    const size_t nCDK = (size_t)in_sizes[5];
    const size_t nCWK = (size_t)in_sizes[6];
    const size_t nCK  = (size_t)in_sizes[7];
    const size_t nEta = (size_t)in_sizes[8];

    float* out = (float*)d_out;
    float* outCDK = out;
    float* outCWK = outCDK + nCDK;
    float* outCK  = outCWK + nCWK;
    float* outEta = outCK  + nCK;

    const int nblk = (AW + WPB - 1) / WPB;      // 1024 @ AW=4.19M
    // ws layout (deterministic regions, no zeroing needed)
    const size_t sz_rcw = (size_t)nblk * WPB * sizeof(u16);
    const size_t sz_rdz = (size_t)nblk * WPB * sizeof(u32);
    const size_t sz_ocw = (size_t)nblk * OCW_STRIDE * sizeof(u16);
    const size_t sz_odz = (size_t)nblk * ODZ_STRIDE * sizeof(u16);
    const size_t ws_need = sz_rcw + sz_rdz + sz_ocw + sz_odz;

    const bool fast = (nCDK == (size_t)ADOC * KDIM) &&
                      (nCWK == (size_t)TDIM * VDIM * KDIM) &&
                      (nCK  == (size_t)TDIM * KDIM) &&
                      (nEta == nCDK) && (ws_size >= ws_need) && (AW > 0);

    if (fast) {
        char* ws = (char*)d_ws;
        u16* rec_cw  = (u16*)ws;
        u32* rec_dz  = (u32*)(ws + sz_rcw);
        u16* offs_cw = (u16*)(ws + sz_rcw + sz_rdz);
        u16* offs_dz = (u16*)(ws + sz_rcw + sz_rdz + sz_ocw);

        hipMemcpyAsync(outCK, inCK, nCK * sizeof(float),
                       hipMemcpyDeviceToDevice, stream);

        p1_route<<<nblk, P1T, 0, stream>>>(
            t_arr, d_arr, w_arr, n_arr, z_arr,
            rec_cw, rec_dz, offs_cw, offs_dz, outCK, AW);

        p2_cwk<<<NB_CW, 256, 0, stream>>>(rec_cw, offs_cw, inCWK, outCWK, nblk);
        p2_dz<<<NB_DZ, 256, 0, stream>>>(rec_dz, offs_dz, inCDK, inEta,
                                         outCDK, outEta, nblk);
    } else {
        hipMemcpyAsync(outCDK, inCDK, nCDK * sizeof(float), hipMemcpyDeviceToDevice, stream);
        hipMemcpyAsync(outCWK, inCWK, nCWK * sizeof(float), hipMemcpyDeviceToDevice, stream);
        hipMemcpyAsync(outCK,  inCK,  nCK  * sizeof(float), hipMemcpyDeviceToDevice, stream);
        hipMemcpyAsync(outEta, inEta, nEta * sizeof(float), hipMemcpyDeviceToDevice, stream);
        const int Kd = KDIM;
        const int T = (int)(nCK / Kd);
        const int V = (int)(nCWK / ((size_t)T * Kd));
        fb_scatter<<<2048, 256, 0, stream>>>(t_arr, d_arr, w_arr, n_arr, z_arr,
                                             outCDK, outCWK, outCK, outEta,
                                             AW, V, Kd);
    }
}